// Round 4
// baseline (1457.542 us; speedup 1.0000x reference)
//
#include <hip/hip_runtime.h>
#include <math.h>

typedef _Float16 half_t;
typedef _Float16 f16x2 __attribute__((ext_vector_type(2)));
typedef _Float16 f16x4 __attribute__((ext_vector_type(4)));
typedef _Float16 f16x8 __attribute__((ext_vector_type(8)));
typedef float f32x4 __attribute__((ext_vector_type(4)));

#define D_PROT 512
#define D_TEXT 2048

// ---------------- utility: fp32 -> fp16 convert (vector x4) ----------------
__global__ void k_cvt4(const float* __restrict__ s, half_t* __restrict__ d, int n4) {
    int i = blockIdx.x * 256 + threadIdx.x;
    if (i < n4) {
        float4 v = ((const float4*)s)[i];
        f16x4 o;
        o.x = (_Float16)v.x; o.y = (_Float16)v.y;
        o.z = (_Float16)v.z; o.w = (_Float16)v.w;
        ((f16x4*)d)[i] = o;
    }
}

// ---------------- degree histogram ----------------
__global__ void k_deg(const int* __restrict__ dst, int E, int* __restrict__ deg) {
    int i = blockIdx.x * 256 + threadIdx.x;
    if (i < E) atomicAdd(&deg[dst[i]], 1);
}

__global__ void k_dinv(const int* __restrict__ deg, float* __restrict__ dinv, int n) {
    int i = blockIdx.x * 256 + threadIdx.x;
    if (i < n) dinv[i] = rsqrtf((float)deg[i] + 1.0f);
}

// ---------------- prefix sum (3-kernel) ----------------
__global__ void k_blocksum(const int* __restrict__ deg, int* __restrict__ bsum, int n) {
    __shared__ int sd[256];
    int i = blockIdx.x * 256 + threadIdx.x;
    sd[threadIdx.x] = (i < n) ? deg[i] : 0;
    __syncthreads();
    for (int s = 128; s > 0; s >>= 1) {
        if (threadIdx.x < s) sd[threadIdx.x] += sd[threadIdx.x + s];
        __syncthreads();
    }
    if (threadIdx.x == 0) bsum[blockIdx.x] = sd[0];
}

__global__ void k_scan_bsum(const int* __restrict__ bsum, int* __restrict__ boff, int nb) {
    if (threadIdx.x == 0 && blockIdx.x == 0) {
        int acc = 0;
        for (int i = 0; i < nb; i++) { boff[i] = acc; acc += bsum[i]; }
    }
}

__global__ void k_scan_final(const int* __restrict__ deg, const int* __restrict__ boff,
                             int* __restrict__ rowptr, int n) {
    __shared__ int sd[256];
    int i = blockIdx.x * 256 + threadIdx.x;
    int v = (i < n) ? deg[i] : 0;
    sd[threadIdx.x] = v;
    __syncthreads();
    for (int s = 1; s < 256; s <<= 1) {
        int t2 = (threadIdx.x >= s) ? sd[threadIdx.x - s] : 0;
        __syncthreads();
        sd[threadIdx.x] += t2;
        __syncthreads();
    }
    if (i < n) rowptr[i + 1] = boff[blockIdx.x] + sd[threadIdx.x];
}

// ---------------- CSR fill (atomic append) ----------------
__global__ void k_fill(const int* __restrict__ src, const int* __restrict__ dst, int E,
                       const int* __restrict__ rowptr, int* __restrict__ fill,
                       int* __restrict__ colidx) {
    int i = blockIdx.x * 256 + threadIdx.x;
    if (i < E) {
        int d = dst[i];
        int pos = atomicAdd(&fill[d], 1);
        colidx[rowptr[d] + pos] = src[i];
    }
}

// ---------------- GraphNorm ----------------
__global__ void k_gnreduce(const float* __restrict__ x, float* __restrict__ sums,
                           float* __restrict__ sumsq, int Nn) {
    int t = threadIdx.x;
    int c = t * 2;
    float s0 = 0, s1 = 0, q0 = 0, q1 = 0;
    for (int r = blockIdx.x; r < Nn; r += gridDim.x) {
        float2 v = *(const float2*)(x + (size_t)r * D_PROT + c);
        s0 += v.x; s1 += v.y; q0 += v.x * v.x; q1 += v.y * v.y;
    }
    atomicAdd(&sums[c], s0);  atomicAdd(&sums[c + 1], s1);
    atomicAdd(&sumsq[c], q0); atomicAdd(&sumsq[c + 1], q1);
}

__global__ void k_gnfinal(const float* __restrict__ sums, const float* __restrict__ sumsq,
                          const float* __restrict__ w, const float* __restrict__ b,
                          const float* __restrict__ ms, float* __restrict__ ab, float invN) {
    int d = blockIdx.x * 256 + threadIdx.x;
    if (d < D_PROT) {
        float mean = sums[d] * invN;
        float m2 = sumsq[d] * invN;
        float mm = mean * ms[d];
        float var = m2 - 2.f * mm * mean + mm * mm;
        float rstd = rsqrtf(var + 1e-5f);
        float a = rstd * w[d];
        ab[d] = a;
        ab[D_PROT + d] = b[d] - mm * a;
    }
}

__global__ void k_gnnorm(const float* __restrict__ x, const float* __restrict__ ab,
                         half_t* __restrict__ h, int n4) {
    int i = blockIdx.x * 256 + threadIdx.x;
    if (i < n4) {
        size_t idx = (size_t)i * 4;
        float4 v = *(const float4*)(x + idx);
        int d = (int)(idx & (D_PROT - 1));
        const float* a = ab;
        const float* bb = ab + D_PROT;
        f16x4 o;
        o.x = (_Float16)(v.x * a[d]     + bb[d]);
        o.y = (_Float16)(v.y * a[d + 1] + bb[d + 1]);
        o.z = (_Float16)(v.z * a[d + 2] + bb[d + 2]);
        o.w = (_Float16)(v.w * a[d + 3] + bb[d + 3]);
        *(f16x4*)(h + idx) = o;
    }
}

// ---------------- SGConv aggregation (CSR gather, 4-way unrolled) ----------------
// out[i] = sum_{s in N(i)} h[s]*dinv[s]*dinv[i] + h[i]*dinv[i]^2
// 128 threads x f16x4 = 512 dims; 4 independent gathers in flight per iter.
__global__ void k_agg(const half_t* __restrict__ h, half_t* __restrict__ out,
                      const int* __restrict__ rowptr, const int* __restrict__ colidx,
                      const float* __restrict__ dinv) {
    int node = blockIdx.x;
    int t = threadIdx.x;
    float di = dinv[node];
    int beg = rowptr[node], end = rowptr[node + 1];
    const f16x4* hp = (const f16x4*)h;
    f16x4 sv = hp[node * 128 + t];
    float dii = di * di;
    float a0 = (float)sv.x * dii, a1 = (float)sv.y * dii;
    float a2 = (float)sv.z * dii, a3 = (float)sv.w * dii;
    int e = beg;
    for (; e + 4 <= end; e += 4) {
        int s0 = colidx[e],     s1 = colidx[e + 1];
        int s2 = colidx[e + 2], s3 = colidx[e + 3];
        float w0 = dinv[s0] * di, w1 = dinv[s1] * di;
        float w2 = dinv[s2] * di, w3 = dinv[s3] * di;
        f16x4 v0 = hp[s0 * 128 + t], v1 = hp[s1 * 128 + t];
        f16x4 v2 = hp[s2 * 128 + t], v3 = hp[s3 * 128 + t];
        a0 += w0 * (float)v0.x + w1 * (float)v1.x + w2 * (float)v2.x + w3 * (float)v3.x;
        a1 += w0 * (float)v0.y + w1 * (float)v1.y + w2 * (float)v2.y + w3 * (float)v3.y;
        a2 += w0 * (float)v0.z + w1 * (float)v1.z + w2 * (float)v2.z + w3 * (float)v3.z;
        a3 += w0 * (float)v0.w + w1 * (float)v1.w + w2 * (float)v2.w + w3 * (float)v3.w;
    }
    for (; e < end; ++e) {
        int s = colidx[e];
        float wgt = dinv[s] * di;
        f16x4 v = hp[s * 128 + t];
        a0 += wgt * (float)v.x; a1 += wgt * (float)v.y;
        a2 += wgt * (float)v.z; a3 += wgt * (float)v.w;
    }
    f16x4 o;
    o.x = (_Float16)a0; o.y = (_Float16)a1; o.z = (_Float16)a2; o.w = (_Float16)a3;
    ((f16x4*)out)[node * 128 + t] = o;
}

// ---------------- 256^2 8-wave deep-pipeline GEMM ----------------
// C[M,N] = A[M,K] @ W[N,K]^T + bias, activation. N % 256 == 0, K % 128 == 0.
// LDS per dbuf (64KB): A rows 0..255 x 64 halves at [0,16384), B at [16384,32768).
// T2 swizzle (verified R3: conflicts=0): read byte ^= ((row&7)<<4); staging source
// pre-swizzled with same involution so linear gload_lds write + swz read = id.
// Deep pipeline: per tile t (buf c=t&1) read ALL 24 frags -> regs; after cluster-1
// MFMA, lgkmcnt(0)+BAR makes buf c fully dead -> stage tile t+2 into buf c (8 GLD).
// End of tile: vmcnt(8) (leaves t+2's 8 outstanding; t+1 fully landed) + BAR.
// Issue->wait distance ~1.7 tiles (~1600cyc) > HBM latency. 2 barriers/tile.
#define FENCE() asm volatile("" ::: "memory")
#define BAR()   do { FENCE(); __builtin_amdgcn_s_barrier(); FENCE(); } while (0)
#define WAITV8() asm volatile("s_waitcnt vmcnt(8)" ::: "memory")
#define WAITV0() asm volatile("s_waitcnt vmcnt(0)" ::: "memory")
#define LGKM0()  asm volatile("s_waitcnt lgkmcnt(0)" ::: "memory")
#define GLD(src, dst) __builtin_amdgcn_global_load_lds( \
    (const __attribute__((address_space(1))) void*)(src), \
    (__attribute__((address_space(3))) void*)(dst), 16, 0, 0)
#define LDF(base, row, kk) \
    (*(const f16x8*)((base) + ((((row) * 128 + (kk) * 64 + fqo)) ^ (((row) & 7) << 4))))
#define MM(mi, nj, A_, B_) \
    acc[mi][nj] = __builtin_amdgcn_mfma_f32_16x16x32_f16(A_, B_, acc[mi][nj], 0, 0, 0)

template <int ACT, typename OUT_T>
__global__ __launch_bounds__(512, 2) void k_gemm8(const half_t* __restrict__ A,
                                                  const half_t* __restrict__ W,
                                                  const float* __restrict__ bias,
                                                  OUT_T* __restrict__ C,
                                                  int M, int N, int K) {
    __shared__ half_t sm[2][32768];
    // XCD-chunked bijective remap (nwg % 8 == 0 in all our launches).
    const int gx = gridDim.x;
    const int nwg = gx * gridDim.y;
    int b = blockIdx.y * gx + blockIdx.x;
    int w8 = ((nwg & 7) == 0) ? (b & 7) * (nwg >> 3) + (b >> 3) : b;
    const int bn = (w8 % gx) * 256;
    const int bm = (w8 / gx) * 256;

    const int t = threadIdx.x;
    const int w = t >> 6, lane = t & 63;
    const int fr = lane & 15, fq = lane >> 4;
    const int fqo = fq * 16;
    const int wm = (w >> 2) * 128, wn = (w & 3) * 64;
    const int NT = K >> 6;

    // staging: load l covers half-range [l*4096 + w*512 + lane*8, +8) (linear LDS
    // write); source index pre-swizzled with the T2 involution.
    int q0 = w * 512 + lane * 8;
    int q1 = 4096 + q0;
    int s0 = q0 ^ (((q0 >> 6) & 7) << 3);
    int s1 = q1 ^ (((q1 >> 6) & 7) << 3);
    int r0 = s0 >> 6, c0 = s0 & 63;
    int r1 = s1 >> 6, c1 = s1 & 63;
    const half_t* gAlo0 = A + (size_t)min(bm + r0, M - 1) * K + c0;
    const half_t* gAlo1 = A + (size_t)min(bm + r1, M - 1) * K + c1;
    const half_t* gAhi0 = A + (size_t)min(bm + 128 + r0, M - 1) * K + c0;
    const half_t* gAhi1 = A + (size_t)min(bm + 128 + r1, M - 1) * K + c1;
    const half_t* gBlo0 = W + (size_t)(bn + r0) * K + c0;
    const half_t* gBlo1 = W + (size_t)(bn + r1) * K + c1;
    const half_t* gBhi0 = W + (size_t)(bn + 128 + r0) * K + c0;
    const half_t* gBhi1 = W + (size_t)(bn + 128 + r1) * K + c1;
    const int dst0 = w * 512;

#define STAGE(cur, kt) do {                                                    \
    GLD(gAlo0 + (size_t)(kt) * 64, &sm[cur][dst0]);                            \
    GLD(gAlo1 + (size_t)(kt) * 64, &sm[cur][4096 + dst0]);                     \
    GLD(gAhi0 + (size_t)(kt) * 64, &sm[cur][8192 + dst0]);                     \
    GLD(gAhi1 + (size_t)(kt) * 64, &sm[cur][12288 + dst0]);                    \
    GLD(gBlo0 + (size_t)(kt) * 64, &sm[cur][16384 + dst0]);                    \
    GLD(gBlo1 + (size_t)(kt) * 64, &sm[cur][20480 + dst0]);                    \
    GLD(gBhi0 + (size_t)(kt) * 64, &sm[cur][24576 + dst0]);                    \
    GLD(gBhi1 + (size_t)(kt) * 64, &sm[cur][28672 + dst0]);                    \
} while (0)

    f32x4 acc[8][4] = {};

    // prologue: tile0 -> buf0, tile1 -> buf1; wait tile0.
    STAGE(0, 0);
    STAGE(1, (NT > 1 ? 1 : 0));
    WAITV8();
    BAR();

    for (int tt = 0; tt < NT; ++tt) {
        const int cur = tt & 1;
        const char* smA = (const char*)&sm[cur][0];
        const char* smB = (const char*)&sm[cur][16384];

        // read ALL frags; order: B, A01 (cluster-1 inputs) first.
        f16x8 bf[4][2], af[8][2];
#pragma unroll
        for (int nj = 0; nj < 4; nj++) {
            bf[nj][0] = LDF(smB, wn + nj * 16 + fr, 0);
            bf[nj][1] = LDF(smB, wn + nj * 16 + fr, 1);
        }
#pragma unroll
        for (int mi = 0; mi < 2; mi++) {
            af[mi][0] = LDF(smA, wm + mi * 16 + fr, 0);
            af[mi][1] = LDF(smA, wm + mi * 16 + fr, 1);
        }
#pragma unroll
        for (int mi = 2; mi < 8; mi++) {
            af[mi][0] = LDF(smA, wm + mi * 16 + fr, 0);
            af[mi][1] = LDF(smA, wm + mi * 16 + fr, 1);
        }
        // cluster 1 (overlaps tail ds_reads' latency)
        __builtin_amdgcn_s_setprio(1);
#pragma unroll
        for (int mi = 0; mi < 2; mi++)
#pragma unroll
            for (int nj = 0; nj < 4; nj++) {
                MM(mi, nj, af[mi][0], bf[nj][0]);
                MM(mi, nj, af[mi][1], bf[nj][1]);
            }
        __builtin_amdgcn_s_setprio(0);
        // all reads drained -> whole buf cur is dead -> safe to overwrite
        LGKM0();
        BAR();
        // stage tile tt+2 into buf cur
        int kt = (tt + 2 < NT) ? tt + 2 : NT - 1;
        STAGE(cur, kt);
        // clusters 2-4
        __builtin_amdgcn_s_setprio(1);
#pragma unroll
        for (int mi = 2; mi < 8; mi++)
#pragma unroll
            for (int nj = 0; nj < 4; nj++) {
                MM(mi, nj, af[mi][0], bf[nj][0]);
                MM(mi, nj, af[mi][1], bf[nj][1]);
            }
        __builtin_amdgcn_s_setprio(0);
        // wait: leaves the 8 loads of tile tt+2 outstanding -> tile tt+1 landed
        WAITV8();
        BAR();
    }
    WAITV0();
#undef STAGE

    // epilogue: D frag mapping col = lane&15, row = (lane>>4)*4 + r
    const int col0 = bn + wn + fr;
#pragma unroll
    for (int mi = 0; mi < 8; mi++) {
        int rb = bm + wm + mi * 16 + fq * 4;
#pragma unroll
        for (int nj = 0; nj < 4; nj++) {
            int col = col0 + nj * 16;
            float bv = bias[col];
#pragma unroll
            for (int r = 0; r < 4; r++) {
                int row = rb + r;
                if (row < M) {
                    float v = acc[mi][nj][r] + bv;
                    if (ACT == 1) v = fmaxf(v, 0.f);
                    if (ACT == 2) v = 0.5f * v * (1.f + erff(v * 0.70710678118f));
                    C[(size_t)row * N + col] = (OUT_T)v;
                }
            }
        }
    }
}

// ---------------- launch ----------------
extern "C" void kernel_launch(void* const* d_in, const int* in_sizes, int n_in,
                              void* d_out, int out_size, void* d_ws, size_t ws_size,
                              hipStream_t stream) {
    const float* x     = (const float*)d_in[0];
    const int*   eidx  = (const int*)d_in[1];
    const float* gn_w  = (const float*)d_in[2];
    const float* gn_b  = (const float*)d_in[3];
    const float* gn_ms = (const float*)d_in[4];
    const float* w1    = (const float*)d_in[5];
    const float* b1    = (const float*)d_in[6];
    const float* w2    = (const float*)d_in[7];
    const float* b2    = (const float*)d_in[8];
    const float* p1    = (const float*)d_in[9];
    const float* pb1   = (const float*)d_in[10];
    const float* p2    = (const float*)d_in[11];
    const float* pb2   = (const float*)d_in[12];

    const int Nn = in_sizes[0] / D_PROT;   // 50000
    const int E  = in_sizes[1] / 2;        // 400000
    const int M  = Nn;

    char* ws = (char*)d_ws;
    size_t off = 0;
    auto alloc = [&](size_t bytes) {
        void* p = ws + off;
        off += (bytes + 255) & ~(size_t)255;
        return p;
    };
    half_t* w1h    = (half_t*)alloc((size_t)D_PROT * D_PROT * 2);
    half_t* w2h    = (half_t*)alloc((size_t)D_PROT * D_PROT * 2);
    half_t* p1h    = (half_t*)alloc((size_t)D_TEXT * D_PROT * 2);
    half_t* p2h    = (half_t*)alloc((size_t)D_TEXT * D_TEXT * 2);
    int*    deg    = (int*)alloc((size_t)Nn * 4);
    float*  dinv   = (float*)alloc((size_t)Nn * 4);
    int*    rowptr = (int*)alloc((size_t)(Nn + 1) * 4);
    int*    fillc  = (int*)alloc((size_t)Nn * 4);
    int*    bsum   = (int*)alloc(1024);
    int*    boff   = (int*)alloc(1024);
    int*    colidx = (int*)alloc((size_t)E * 4);
    float*  sums   = (float*)alloc(D_PROT * 4);
    float*  sumsq  = (float*)alloc(D_PROT * 4);
    float*  gnab   = (float*)alloc(2 * D_PROT * 4);
    half_t* buf1   = (half_t*)alloc((size_t)Nn * D_PROT * 2);
    half_t* buf2   = (half_t*)alloc((size_t)Nn * D_PROT * 2);
    half_t* big    = (half_t*)alloc((size_t)Nn * D_TEXT * 2);

    const int* esrc = eidx;
    const int* edst = eidx + E;

    hipMemsetAsync(deg, 0, (size_t)Nn * 4, stream);
    hipMemsetAsync(fillc, 0, (size_t)Nn * 4, stream);
    hipMemsetAsync(rowptr, 0, (size_t)(Nn + 1) * 4, stream);
    hipMemsetAsync(sums, 0, D_PROT * 4, stream);
    hipMemsetAsync(sumsq, 0, D_PROT * 4, stream);

    k_cvt4<<<(D_PROT * D_PROT / 4 + 255) / 256, 256, 0, stream>>>(w1, w1h, D_PROT * D_PROT / 4);
    k_cvt4<<<(D_PROT * D_PROT / 4 + 255) / 256, 256, 0, stream>>>(w2, w2h, D_PROT * D_PROT / 4);
    k_cvt4<<<(D_TEXT * D_PROT / 4 + 255) / 256, 256, 0, stream>>>(p1, p1h, D_TEXT * D_PROT / 4);
    k_cvt4<<<(D_TEXT * D_TEXT / 4 + 255) / 256, 256, 0, stream>>>(p2, p2h, D_TEXT * D_TEXT / 4);

    int eb = (E + 255) / 256;
    int nb = (Nn + 255) / 256;
    k_deg<<<eb, 256, 0, stream>>>(edst, E, deg);
    k_dinv<<<nb, 256, 0, stream>>>(deg, dinv, Nn);
    k_blocksum<<<nb, 256, 0, stream>>>(deg, bsum, Nn);
    k_scan_bsum<<<1, 1, 0, stream>>>(bsum, boff, nb);
    k_scan_final<<<nb, 256, 0, stream>>>(deg, boff, rowptr, Nn);
    k_fill<<<eb, 256, 0, stream>>>(esrc, edst, E, rowptr, fillc, colidx);

    k_gnreduce<<<256, 256, 0, stream>>>(x, sums, sumsq, Nn);
    k_gnfinal<<<2, 256, 0, stream>>>(sums, sumsq, gn_w, gn_b, gn_ms, gnab, 1.0f / (float)Nn);
    int n4 = Nn * D_PROT / 4;
    k_gnnorm<<<(n4 + 255) / 256, 256, 0, stream>>>(x, gnab, buf1, n4);

    const int mt256 = (M + 255) / 256;

    // conv1: agg -> gemm+relu
    k_agg<<<Nn, 128, 0, stream>>>(buf1, buf2, rowptr, colidx, dinv);
    {
        dim3 g(D_PROT / 256, mt256);
        k_gemm8<1, half_t><<<g, 512, 0, stream>>>(buf2, w1h, b1, buf1, M, D_PROT, D_PROT);
    }
    // conv2
    k_agg<<<Nn, 128, 0, stream>>>(buf1, buf2, rowptr, colidx, dinv);
    {
        dim3 g(D_PROT / 256, mt256);
        k_gemm8<1, half_t><<<g, 512, 0, stream>>>(buf2, w2h, b2, buf1, M, D_PROT, D_PROT);
    }
    // proj1 + gelu
    {
        dim3 g(D_TEXT / 256, mt256);
        k_gemm8<2, half_t><<<g, 512, 0, stream>>>(buf1, p1h, pb1, big, M, D_TEXT, D_PROT);
    }
    // proj2 -> fp32 out
    {
        dim3 g(D_TEXT / 256, mt256);
        k_gemm8<0, float><<<g, 512, 0, stream>>>(big, p2h, pb2, (float*)d_out, M, D_TEXT, D_TEXT);
    }
}

// Round 5
// 1330.154 us; speedup vs baseline: 1.0958x; 1.0958x over previous
//
#include <hip/hip_runtime.h>
#include <math.h>

typedef _Float16 half_t;
typedef _Float16 f16x2 __attribute__((ext_vector_type(2)));
typedef _Float16 f16x4 __attribute__((ext_vector_type(4)));
typedef _Float16 f16x8 __attribute__((ext_vector_type(8)));
typedef float f32x4 __attribute__((ext_vector_type(4)));

#define D_PROT 512
#define D_TEXT 2048

// ---------------- utility: fp32 -> fp16 convert (vector x4) ----------------
__global__ void k_cvt4(const float* __restrict__ s, half_t* __restrict__ d, int n4) {
    int i = blockIdx.x * 256 + threadIdx.x;
    if (i < n4) {
        float4 v = ((const float4*)s)[i];
        f16x4 o;
        o.x = (_Float16)v.x; o.y = (_Float16)v.y;
        o.z = (_Float16)v.z; o.w = (_Float16)v.w;
        ((f16x4*)d)[i] = o;
    }
}

// ---------------- degree histogram ----------------
__global__ void k_deg(const int* __restrict__ dst, int E, int* __restrict__ deg) {
    int i = blockIdx.x * 256 + threadIdx.x;
    if (i < E) atomicAdd(&deg[dst[i]], 1);
}

__global__ void k_dinv(const int* __restrict__ deg, float* __restrict__ dinv, int n) {
    int i = blockIdx.x * 256 + threadIdx.x;
    if (i < n) dinv[i] = rsqrtf((float)deg[i] + 1.0f);
}

// ---------------- prefix sum (3-kernel) ----------------
__global__ void k_blocksum(const int* __restrict__ deg, int* __restrict__ bsum, int n) {
    __shared__ int sd[256];
    int i = blockIdx.x * 256 + threadIdx.x;
    sd[threadIdx.x] = (i < n) ? deg[i] : 0;
    __syncthreads();
    for (int s = 128; s > 0; s >>= 1) {
        if (threadIdx.x < s) sd[threadIdx.x] += sd[threadIdx.x + s];
        __syncthreads();
    }
    if (threadIdx.x == 0) bsum[blockIdx.x] = sd[0];
}

__global__ void k_scan_bsum(const int* __restrict__ bsum, int* __restrict__ boff, int nb) {
    if (threadIdx.x == 0 && blockIdx.x == 0) {
        int acc = 0;
        for (int i = 0; i < nb; i++) { boff[i] = acc; acc += bsum[i]; }
    }
}

__global__ void k_scan_final(const int* __restrict__ deg, const int* __restrict__ boff,
                             int* __restrict__ rowptr, int n) {
    __shared__ int sd[256];
    int i = blockIdx.x * 256 + threadIdx.x;
    int v = (i < n) ? deg[i] : 0;
    sd[threadIdx.x] = v;
    __syncthreads();
    for (int s = 1; s < 256; s <<= 1) {
        int t2 = (threadIdx.x >= s) ? sd[threadIdx.x - s] : 0;
        __syncthreads();
        sd[threadIdx.x] += t2;
        __syncthreads();
    }
    if (i < n) rowptr[i + 1] = boff[blockIdx.x] + sd[threadIdx.x];
}

// ---------------- CSR fill (atomic append) ----------------
__global__ void k_fill(const int* __restrict__ src, const int* __restrict__ dst, int E,
                       const int* __restrict__ rowptr, int* __restrict__ fill,
                       int* __restrict__ colidx) {
    int i = blockIdx.x * 256 + threadIdx.x;
    if (i < E) {
        int d = dst[i];
        int pos = atomicAdd(&fill[d], 1);
        colidx[rowptr[d] + pos] = src[i];
    }
}

// ---------------- GraphNorm ----------------
__global__ void k_gnreduce(const float* __restrict__ x, float* __restrict__ sums,
                           float* __restrict__ sumsq, int Nn) {
    int t = threadIdx.x;
    int c = t * 2;
    float s0 = 0, s1 = 0, q0 = 0, q1 = 0;
    for (int r = blockIdx.x; r < Nn; r += gridDim.x) {
        float2 v = *(const float2*)(x + (size_t)r * D_PROT + c);
        s0 += v.x; s1 += v.y; q0 += v.x * v.x; q1 += v.y * v.y;
    }
    atomicAdd(&sums[c], s0);  atomicAdd(&sums[c + 1], s1);
    atomicAdd(&sumsq[c], q0); atomicAdd(&sumsq[c + 1], q1);
}

__global__ void k_gnfinal(const float* __restrict__ sums, const float* __restrict__ sumsq,
                          const float* __restrict__ w, const float* __restrict__ b,
                          const float* __restrict__ ms, float* __restrict__ ab, float invN) {
    int d = blockIdx.x * 256 + threadIdx.x;
    if (d < D_PROT) {
        float mean = sums[d] * invN;
        float m2 = sumsq[d] * invN;
        float mm = mean * ms[d];
        float var = m2 - 2.f * mm * mean + mm * mm;
        float rstd = rsqrtf(var + 1e-5f);
        float a = rstd * w[d];
        ab[d] = a;
        ab[D_PROT + d] = b[d] - mm * a;
    }
}

__global__ void k_gnnorm(const float* __restrict__ x, const float* __restrict__ ab,
                         half_t* __restrict__ h, int n4) {
    int i = blockIdx.x * 256 + threadIdx.x;
    if (i < n4) {
        size_t idx = (size_t)i * 4;
        float4 v = *(const float4*)(x + idx);
        int d = (int)(idx & (D_PROT - 1));
        const float* a = ab;
        const float* bb = ab + D_PROT;
        f16x4 o;
        o.x = (_Float16)(v.x * a[d]     + bb[d]);
        o.y = (_Float16)(v.y * a[d + 1] + bb[d + 1]);
        o.z = (_Float16)(v.z * a[d + 2] + bb[d + 2]);
        o.w = (_Float16)(v.w * a[d + 3] + bb[d + 3]);
        *(f16x4*)(h + idx) = o;
    }
}

// ---------------- SGConv aggregation (CSR gather, 4-way unrolled) ----------------
__global__ void k_agg(const half_t* __restrict__ h, half_t* __restrict__ out,
                      const int* __restrict__ rowptr, const int* __restrict__ colidx,
                      const float* __restrict__ dinv) {
    int node = blockIdx.x;
    int t = threadIdx.x;
    float di = dinv[node];
    int beg = rowptr[node], end = rowptr[node + 1];
    const f16x4* hp = (const f16x4*)h;
    f16x4 sv = hp[node * 128 + t];
    float dii = di * di;
    float a0 = (float)sv.x * dii, a1 = (float)sv.y * dii;
    float a2 = (float)sv.z * dii, a3 = (float)sv.w * dii;
    int e = beg;
    for (; e + 4 <= end; e += 4) {
        int s0 = colidx[e],     s1 = colidx[e + 1];
        int s2 = colidx[e + 2], s3 = colidx[e + 3];
        float w0 = dinv[s0] * di, w1 = dinv[s1] * di;
        float w2 = dinv[s2] * di, w3 = dinv[s3] * di;
        f16x4 v0 = hp[s0 * 128 + t], v1 = hp[s1 * 128 + t];
        f16x4 v2 = hp[s2 * 128 + t], v3 = hp[s3 * 128 + t];
        a0 += w0 * (float)v0.x + w1 * (float)v1.x + w2 * (float)v2.x + w3 * (float)v3.x;
        a1 += w0 * (float)v0.y + w1 * (float)v1.y + w2 * (float)v2.y + w3 * (float)v3.y;
        a2 += w0 * (float)v0.z + w1 * (float)v1.z + w2 * (float)v2.z + w3 * (float)v3.z;
        a3 += w0 * (float)v0.w + w1 * (float)v1.w + w2 * (float)v2.w + w3 * (float)v3.w;
    }
    for (; e < end; ++e) {
        int s = colidx[e];
        float wgt = dinv[s] * di;
        f16x4 v = hp[s * 128 + t];
        a0 += wgt * (float)v.x; a1 += wgt * (float)v.y;
        a2 += wgt * (float)v.z; a3 += wgt * (float)v.w;
    }
    f16x4 o;
    o.x = (_Float16)a0; o.y = (_Float16)a1; o.z = (_Float16)a2; o.w = (_Float16)a3;
    ((f16x4*)out)[node * 128 + t] = o;
}

// ---------------- 256^2 8-wave 3-phase GEMM, deep A+B prefetch ----------------
// C[M,N] = A[M,K] @ W[N,K]^T + bias, activation. N % 256 == 0, K % 64 == 0.
// LDS per dbuf (64KB): A rows 0..255 x 64 halves at [0,16384), B at [16384,32768).
// T2 swizzle (R3-verified conflicts=0): read byte ^= ((row&7)<<4); staging source
// pre-swizzled with the same involution; linear gload_lds write + swz read = id.
// Schedule per tile t (buf cur = t&1), 3 phases:
//  P1: ds_read B(8 frags) + A mi0..3. BAR. MFMA mi0,1. BAR.
//  P2: ds_read A mi4..7; GLD Blo(t+2)->cur; LGKM0 (block-wide A/B drain). BAR.
//      MFMA mi2,3. BAR.
//  P3: GLD A(t+2)x4 + Bhi(t+2)x2 -> cur (safe: P2's LGKM0+BAR proved cur fully
//      drained). BAR. MFMA mi4..7. WAITV8 (drains tile t+1's 8 loads; leaves
//      t+2's 8 in flight). BAR.
// A issue->wait distance: ~5 phases (>= 2x HBM latency). Never vmcnt(0) in loop.
#define FENCE() asm volatile("" ::: "memory")
#define BAR()   do { FENCE(); __builtin_amdgcn_s_barrier(); FENCE(); } while (0)
#define WAITV8() asm volatile("s_waitcnt vmcnt(8)" ::: "memory")
#define WAITV0() asm volatile("s_waitcnt vmcnt(0)" ::: "memory")
#define LGKM0()  asm volatile("s_waitcnt lgkmcnt(0)" ::: "memory")
#define GLD(src, dst) __builtin_amdgcn_global_load_lds( \
    (const __attribute__((address_space(1))) void*)(src), \
    (__attribute__((address_space(3))) void*)(dst), 16, 0, 0)
#define LDF(base, row, kk) \
    (*(const f16x8*)((base) + ((((row) * 128 + (kk) * 64 + fqo)) ^ (((row) & 7) << 4))))
#define MM(mi, nj, A_, B_) \
    acc[mi][nj] = __builtin_amdgcn_mfma_f32_16x16x32_f16(A_, B_, acc[mi][nj], 0, 0, 0)

template <int ACT, typename OUT_T>
__global__ __launch_bounds__(512, 2) void k_gemm8(const half_t* __restrict__ A,
                                                  const half_t* __restrict__ W,
                                                  const float* __restrict__ bias,
                                                  OUT_T* __restrict__ C,
                                                  int M, int N, int K) {
    __shared__ half_t sm[2][32768];
    // XCD-chunked bijective remap (nwg % 8 == 0 in all our launches).
    const int gx = gridDim.x;
    const int nwg = gx * gridDim.y;
    int b = blockIdx.y * gx + blockIdx.x;
    int w8 = ((nwg & 7) == 0) ? (b & 7) * (nwg >> 3) + (b >> 3) : b;
    const int bn = (w8 % gx) * 256;
    const int bm = (w8 / gx) * 256;

    const int t = threadIdx.x;
    const int w = t >> 6, lane = t & 63;
    const int fr = lane & 15, fq = lane >> 4;
    const int fqo = fq * 16;
    const int wm = (w >> 2) * 128, wn = (w & 3) * 64;
    const int NT = K >> 6;

    // staging: load l covers half-range [l*4096 + w*512 + lane*8, +8) (linear LDS
    // write); source index pre-swizzled with the T2 involution.
    int q0 = w * 512 + lane * 8;
    int q1 = 4096 + q0;
    int s0 = q0 ^ (((q0 >> 6) & 7) << 3);
    int s1 = q1 ^ (((q1 >> 6) & 7) << 3);
    int r0 = s0 >> 6, c0 = s0 & 63;
    int r1 = s1 >> 6, c1 = s1 & 63;
    const half_t* gAlo0 = A + (size_t)min(bm + r0, M - 1) * K + c0;
    const half_t* gAlo1 = A + (size_t)min(bm + r1, M - 1) * K + c1;
    const half_t* gAhi0 = A + (size_t)min(bm + 128 + r0, M - 1) * K + c0;
    const half_t* gAhi1 = A + (size_t)min(bm + 128 + r1, M - 1) * K + c1;
    const half_t* gBlo0 = W + (size_t)(bn + r0) * K + c0;
    const half_t* gBlo1 = W + (size_t)(bn + r1) * K + c1;
    const half_t* gBhi0 = W + (size_t)(bn + 128 + r0) * K + c0;
    const half_t* gBhi1 = W + (size_t)(bn + 128 + r1) * K + c1;
    const int dst0 = w * 512;

#define STAGE_A(cur, kt) do {                                                  \
    GLD(gAlo0 + (size_t)(kt) * 64, &sm[cur][dst0]);                            \
    GLD(gAlo1 + (size_t)(kt) * 64, &sm[cur][4096 + dst0]);                     \
    GLD(gAhi0 + (size_t)(kt) * 64, &sm[cur][8192 + dst0]);                     \
    GLD(gAhi1 + (size_t)(kt) * 64, &sm[cur][12288 + dst0]);                    \
} while (0)
#define STAGE_BLO(cur, kt) do {                                                \
    GLD(gBlo0 + (size_t)(kt) * 64, &sm[cur][16384 + dst0]);                    \
    GLD(gBlo1 + (size_t)(kt) * 64, &sm[cur][20480 + dst0]);                    \
} while (0)
#define STAGE_BHI(cur, kt) do {                                                \
    GLD(gBhi0 + (size_t)(kt) * 64, &sm[cur][24576 + dst0]);                    \
    GLD(gBhi1 + (size_t)(kt) * 64, &sm[cur][28672 + dst0]);                    \
} while (0)

    f32x4 acc[8][4] = {};

    // prologue: tile0 all 8 units -> buf0 (Blo, A, Bhi order); tile1 -> buf1.
    STAGE_BLO(0, 0); STAGE_A(0, 0); STAGE_BHI(0, 0);
    {
        int k1 = (NT > 1) ? 1 : 0;
        STAGE_BLO(1, k1); STAGE_A(1, k1); STAGE_BHI(1, k1);
    }
    WAITV8();   // tile0 landed; tile1's 8 in flight
    BAR();

    for (int tt = 0; tt < NT; ++tt) {
        const int cur = tt & 1;
        const char* smA = (const char*)&sm[cur][0];
        const char* smB = (const char*)&sm[cur][16384];
        const int kt = (tt + 2 < NT) ? tt + 2 : NT - 1;

        f16x8 bf[4][2], af[8][2];
        // ---- P1: read B all + A mi0..3 ----
#pragma unroll
        for (int nj = 0; nj < 4; nj++) {
            bf[nj][0] = LDF(smB, wn + nj * 16 + fr, 0);
            bf[nj][1] = LDF(smB, wn + nj * 16 + fr, 1);
        }
#pragma unroll
        for (int mi = 0; mi < 4; mi++) {
            af[mi][0] = LDF(smA, wm + mi * 16 + fr, 0);
            af[mi][1] = LDF(smA, wm + mi * 16 + fr, 1);
        }
        BAR();
        __builtin_amdgcn_s_setprio(1);
#pragma unroll
        for (int mi = 0; mi < 2; mi++)
#pragma unroll
            for (int nj = 0; nj < 4; nj++) {
                MM(mi, nj, af[mi][0], bf[nj][0]);
                MM(mi, nj, af[mi][1], bf[nj][1]);
            }
        __builtin_amdgcn_s_setprio(0);
        BAR();
        // ---- P2: read A mi4..7; stage Blo(t+2)->cur; block-wide lgkm drain ----
#pragma unroll
        for (int mi = 4; mi < 8; mi++) {
            af[mi][0] = LDF(smA, wm + mi * 16 + fr, 0);
            af[mi][1] = LDF(smA, wm + mi * 16 + fr, 1);
        }
        STAGE_BLO(cur, kt);
        LGKM0();   // all of this wave's ds_reads from buf cur drained
        BAR();     // => block-wide: buf cur fully drained; safe to overwrite
        __builtin_amdgcn_s_setprio(1);
#pragma unroll
        for (int mi = 2; mi < 4; mi++)
#pragma unroll
            for (int nj = 0; nj < 4; nj++) {
                MM(mi, nj, af[mi][0], bf[nj][0]);
                MM(mi, nj, af[mi][1], bf[nj][1]);
            }
        __builtin_amdgcn_s_setprio(0);
        BAR();
        // ---- P3: stage A(t+2)+Bhi(t+2)->cur; MFMA mi4..7; counted wait ----
        STAGE_A(cur, kt);
        STAGE_BHI(cur, kt);
        BAR();
        __builtin_amdgcn_s_setprio(1);
#pragma unroll
        for (int mi = 4; mi < 8; mi++)
#pragma unroll
            for (int nj = 0; nj < 4; nj++) {
                MM(mi, nj, af[mi][0], bf[nj][0]);
                MM(mi, nj, af[mi][1], bf[nj][1]);
            }
        __builtin_amdgcn_s_setprio(0);
        WAITV8();  // tile t+1 fully landed; t+2's 8 stay in flight
        BAR();
    }
    WAITV0();
#undef STAGE_A
#undef STAGE_BLO
#undef STAGE_BHI

    // epilogue: D frag mapping col = lane&15, row = (lane>>4)*4 + r
    const int col0 = bn + wn + fr;
#pragma unroll
    for (int mi = 0; mi < 8; mi++) {
        int rb = bm + wm + mi * 16 + fq * 4;
#pragma unroll
        for (int nj = 0; nj < 4; nj++) {
            int col = col0 + nj * 16;
            float bv = bias[col];
#pragma unroll
            for (int r = 0; r < 4; r++) {
                int row = rb + r;
                if (row < M) {
                    float v = acc[mi][nj][r] + bv;
                    if (ACT == 1) v = fmaxf(v, 0.f);
                    if (ACT == 2) v = 0.5f * v * (1.f + erff(v * 0.70710678118f));
                    C[(size_t)row * N + col] = (OUT_T)v;
                }
            }
        }
    }
}

// ---------------- launch ----------------
extern "C" void kernel_launch(void* const* d_in, const int* in_sizes, int n_in,
                              void* d_out, int out_size, void* d_ws, size_t ws_size,
                              hipStream_t stream) {
    const float* x     = (const float*)d_in[0];
    const int*   eidx  = (const int*)d_in[1];
    const float* gn_w  = (const float*)d_in[2];
    const float* gn_b  = (const float*)d_in[3];
    const float* gn_ms = (const float*)d_in[4];
    const float* w1    = (const float*)d_in[5];
    const float* b1    = (const float*)d_in[6];
    const float* w2    = (const float*)d_in[7];
    const float* b2    = (const float*)d_in[8];
    const float* p1    = (const float*)d_in[9];
    const float* pb1   = (const float*)d_in[10];
    const float* p2    = (const float*)d_in[11];
    const float* pb2   = (const float*)d_in[12];

    const int Nn = in_sizes[0] / D_PROT;   // 50000
    const int E  = in_sizes[1] / 2;        // 400000
    const int M  = Nn;

    char* ws = (char*)d_ws;
    size_t off = 0;
    auto alloc = [&](size_t bytes) {
        void* p = ws + off;
        off += (bytes + 255) & ~(size_t)255;
        return p;
    };
    half_t* w1h    = (half_t*)alloc((size_t)D_PROT * D_PROT * 2);
    half_t* w2h    = (half_t*)alloc((size_t)D_PROT * D_PROT * 2);
    half_t* p1h    = (half_t*)alloc((size_t)D_TEXT * D_PROT * 2);
    half_t* p2h    = (half_t*)alloc((size_t)D_TEXT * D_TEXT * 2);
    int*    deg    = (int*)alloc((size_t)Nn * 4);
    float*  dinv   = (float*)alloc((size_t)Nn * 4);
    int*    rowptr = (int*)alloc((size_t)(Nn + 1) * 4);
    int*    fillc  = (int*)alloc((size_t)Nn * 4);
    int*    bsum   = (int*)alloc(1024);
    int*    boff   = (int*)alloc(1024);
    int*    colidx = (int*)alloc((size_t)E * 4);
    float*  sums   = (float*)alloc(D_PROT * 4);
    float*  sumsq  = (float*)alloc(D_PROT * 4);
    float*  gnab   = (float*)alloc(2 * D_PROT * 4);
    half_t* buf1   = (half_t*)alloc((size_t)Nn * D_PROT * 2);
    half_t* buf2   = (half_t*)alloc((size_t)Nn * D_PROT * 2);
    half_t* big    = (half_t*)alloc((size_t)Nn * D_TEXT * 2);

    const int* esrc = eidx;
    const int* edst = eidx + E;

    hipMemsetAsync(deg, 0, (size_t)Nn * 4, stream);
    hipMemsetAsync(fillc, 0, (size_t)Nn * 4, stream);
    hipMemsetAsync(rowptr, 0, (size_t)(Nn + 1) * 4, stream);
    hipMemsetAsync(sums, 0, D_PROT * 4, stream);
    hipMemsetAsync(sumsq, 0, D_PROT * 4, stream);

    k_cvt4<<<(D_PROT * D_PROT / 4 + 255) / 256, 256, 0, stream>>>(w1, w1h, D_PROT * D_PROT / 4);
    k_cvt4<<<(D_PROT * D_PROT / 4 + 255) / 256, 256, 0, stream>>>(w2, w2h, D_PROT * D_PROT / 4);
    k_cvt4<<<(D_TEXT * D_PROT / 4 + 255) / 256, 256, 0, stream>>>(p1, p1h, D_TEXT * D_PROT / 4);
    k_cvt4<<<(D_TEXT * D_TEXT / 4 + 255) / 256, 256, 0, stream>>>(p2, p2h, D_TEXT * D_TEXT / 4);

    int eb = (E + 255) / 256;
    int nb = (Nn + 255) / 256;
    k_deg<<<eb, 256, 0, stream>>>(edst, E, deg);
    k_dinv<<<nb, 256, 0, stream>>>(deg, dinv, Nn);
    k_blocksum<<<nb, 256, 0, stream>>>(deg, bsum, Nn);
    k_scan_bsum<<<1, 1, 0, stream>>>(bsum, boff, nb);
    k_scan_final<<<nb, 256, 0, stream>>>(deg, boff, rowptr, Nn);
    k_fill<<<eb, 256, 0, stream>>>(esrc, edst, E, rowptr, fillc, colidx);

    k_gnreduce<<<256, 256, 0, stream>>>(x, sums, sumsq, Nn);
    k_gnfinal<<<2, 256, 0, stream>>>(sums, sumsq, gn_w, gn_b, gn_ms, gnab, 1.0f / (float)Nn);
    int n4 = Nn * D_PROT / 4;
    k_gnnorm<<<(n4 + 255) / 256, 256, 0, stream>>>(x, gnab, buf1, n4);

    const int mt256 = (M + 255) / 256;

    // conv1: agg -> gemm+relu
    k_agg<<<Nn, 128, 0, stream>>>(buf1, buf2, rowptr, colidx, dinv);
    {
        dim3 g(D_PROT / 256, mt256);
        k_gemm8<1, half_t><<<g, 512, 0, stream>>>(buf2, w1h, b1, buf1, M, D_PROT, D_PROT);
    }
    // conv2
    k_agg<<<Nn, 128, 0, stream>>>(buf1, buf2, rowptr, colidx, dinv);
    {
        dim3 g(D_PROT / 256, mt256);
        k_gemm8<1, half_t><<<g, 512, 0, stream>>>(buf2, w2h, b2, buf1, M, D_PROT, D_PROT);
    }
    // proj1 + gelu
    {
        dim3 g(D_TEXT / 256, mt256);
        k_gemm8<2, half_t><<<g, 512, 0, stream>>>(buf1, p1h, pb1, big, M, D_TEXT, D_PROT);
    }
    // proj2 -> fp32 out
    {
        dim3 g(D_TEXT / 256, mt256);
        k_gemm8<0, float><<<g, 512, 0, stream>>>(big, p2h, pb2, (float*)d_out, M, D_TEXT, D_TEXT);
    }
}

// Round 6
// 1252.709 us; speedup vs baseline: 1.1635x; 1.0618x over previous
//
#include <hip/hip_runtime.h>
#include <math.h>

typedef _Float16 half_t;
typedef _Float16 f16x2 __attribute__((ext_vector_type(2)));
typedef _Float16 f16x4 __attribute__((ext_vector_type(4)));
typedef _Float16 f16x8 __attribute__((ext_vector_type(8)));
typedef float f32x4 __attribute__((ext_vector_type(4)));

#define D_PROT 512
#define D_TEXT 2048

// ---------------- utility: fp32 -> fp16 convert (vector x4) ----------------
__global__ void k_cvt4(const float* __restrict__ s, half_t* __restrict__ d, int n4) {
    int i = blockIdx.x * 256 + threadIdx.x;
    if (i < n4) {
        float4 v = ((const float4*)s)[i];
        f16x4 o;
        o.x = (_Float16)v.x; o.y = (_Float16)v.y;
        o.z = (_Float16)v.z; o.w = (_Float16)v.w;
        ((f16x4*)d)[i] = o;
    }
}

// ---------------- degree histogram ----------------
__global__ void k_deg(const int* __restrict__ dst, int E, int* __restrict__ deg) {
    int i = blockIdx.x * 256 + threadIdx.x;
    if (i < E) atomicAdd(&deg[dst[i]], 1);
}

__global__ void k_dinv(const int* __restrict__ deg, float* __restrict__ dinv, int n) {
    int i = blockIdx.x * 256 + threadIdx.x;
    if (i < n) dinv[i] = rsqrtf((float)deg[i] + 1.0f);
}

// ---------------- prefix sum (3-kernel) ----------------
__global__ void k_blocksum(const int* __restrict__ deg, int* __restrict__ bsum, int n) {
    __shared__ int sd[256];
    int i = blockIdx.x * 256 + threadIdx.x;
    sd[threadIdx.x] = (i < n) ? deg[i] : 0;
    __syncthreads();
    for (int s = 128; s > 0; s >>= 1) {
        if (threadIdx.x < s) sd[threadIdx.x] += sd[threadIdx.x + s];
        __syncthreads();
    }
    if (threadIdx.x == 0) bsum[blockIdx.x] = sd[0];
}

__global__ void k_scan_bsum(const int* __restrict__ bsum, int* __restrict__ boff, int nb) {
    if (threadIdx.x == 0 && blockIdx.x == 0) {
        int acc = 0;
        for (int i = 0; i < nb; i++) { boff[i] = acc; acc += bsum[i]; }
    }
}

__global__ void k_scan_final(const int* __restrict__ deg, const int* __restrict__ boff,
                             int* __restrict__ rowptr, int n) {
    __shared__ int sd[256];
    int i = blockIdx.x * 256 + threadIdx.x;
    int v = (i < n) ? deg[i] : 0;
    sd[threadIdx.x] = v;
    __syncthreads();
    for (int s = 1; s < 256; s <<= 1) {
        int t2 = (threadIdx.x >= s) ? sd[threadIdx.x - s] : 0;
        __syncthreads();
        sd[threadIdx.x] += t2;
        __syncthreads();
    }
    if (i < n) rowptr[i + 1] = boff[blockIdx.x] + sd[threadIdx.x];
}

// ---------------- CSR fill (atomic append) ----------------
__global__ void k_fill(const int* __restrict__ src, const int* __restrict__ dst, int E,
                       const int* __restrict__ rowptr, int* __restrict__ fill,
                       int* __restrict__ colidx) {
    int i = blockIdx.x * 256 + threadIdx.x;
    if (i < E) {
        int d = dst[i];
        int pos = atomicAdd(&fill[d], 1);
        colidx[rowptr[d] + pos] = src[i];
    }
}

// ---------------- GraphNorm ----------------
__global__ void k_gnreduce(const float* __restrict__ x, float* __restrict__ sums,
                           float* __restrict__ sumsq, int Nn) {
    int t = threadIdx.x;
    int c = t * 2;
    float s0 = 0, s1 = 0, q0 = 0, q1 = 0;
    for (int r = blockIdx.x; r < Nn; r += gridDim.x) {
        float2 v = *(const float2*)(x + (size_t)r * D_PROT + c);
        s0 += v.x; s1 += v.y; q0 += v.x * v.x; q1 += v.y * v.y;
    }
    atomicAdd(&sums[c], s0);  atomicAdd(&sums[c + 1], s1);
    atomicAdd(&sumsq[c], q0); atomicAdd(&sumsq[c + 1], q1);
}

__global__ void k_gnfinal(const float* __restrict__ sums, const float* __restrict__ sumsq,
                          const float* __restrict__ w, const float* __restrict__ b,
                          const float* __restrict__ ms, float* __restrict__ ab, float invN) {
    int d = blockIdx.x * 256 + threadIdx.x;
    if (d < D_PROT) {
        float mean = sums[d] * invN;
        float m2 = sumsq[d] * invN;
        float mm = mean * ms[d];
        float var = m2 - 2.f * mm * mean + mm * mm;
        float rstd = rsqrtf(var + 1e-5f);
        float a = rstd * w[d];
        ab[d] = a;
        ab[D_PROT + d] = b[d] - mm * a;
    }
}

__global__ void k_gnnorm(const float* __restrict__ x, const float* __restrict__ ab,
                         half_t* __restrict__ h, int n4) {
    int i = blockIdx.x * 256 + threadIdx.x;
    if (i < n4) {
        size_t idx = (size_t)i * 4;
        float4 v = *(const float4*)(x + idx);
        int d = (int)(idx & (D_PROT - 1));
        const float* a = ab;
        const float* bb = ab + D_PROT;
        f16x4 o;
        o.x = (_Float16)(v.x * a[d]     + bb[d]);
        o.y = (_Float16)(v.y * a[d + 1] + bb[d + 1]);
        o.z = (_Float16)(v.z * a[d + 2] + bb[d + 2]);
        o.w = (_Float16)(v.w * a[d + 3] + bb[d + 3]);
        *(f16x4*)(h + idx) = o;
    }
}

// ---------------- SGConv aggregation (CSR gather, 4-way unrolled) ----------------
__global__ void k_agg(const half_t* __restrict__ h, half_t* __restrict__ out,
                      const int* __restrict__ rowptr, const int* __restrict__ colidx,
                      const float* __restrict__ dinv) {
    int node = blockIdx.x;
    int t = threadIdx.x;
    float di = dinv[node];
    int beg = rowptr[node], end = rowptr[node + 1];
    const f16x4* hp = (const f16x4*)h;
    f16x4 sv = hp[node * 128 + t];
    float dii = di * di;
    float a0 = (float)sv.x * dii, a1 = (float)sv.y * dii;
    float a2 = (float)sv.z * dii, a3 = (float)sv.w * dii;
    int e = beg;
    for (; e + 4 <= end; e += 4) {
        int s0 = colidx[e],     s1 = colidx[e + 1];
        int s2 = colidx[e + 2], s3 = colidx[e + 3];
        float w0 = dinv[s0] * di, w1 = dinv[s1] * di;
        float w2 = dinv[s2] * di, w3 = dinv[s3] * di;
        f16x4 v0 = hp[s0 * 128 + t], v1 = hp[s1 * 128 + t];
        f16x4 v2 = hp[s2 * 128 + t], v3 = hp[s3 * 128 + t];
        a0 += w0 * (float)v0.x + w1 * (float)v1.x + w2 * (float)v2.x + w3 * (float)v3.x;
        a1 += w0 * (float)v0.y + w1 * (float)v1.y + w2 * (float)v2.y + w3 * (float)v3.y;
        a2 += w0 * (float)v0.z + w1 * (float)v1.z + w2 * (float)v2.z + w3 * (float)v3.z;
        a3 += w0 * (float)v0.w + w1 * (float)v1.w + w2 * (float)v2.w + w3 * (float)v3.w;
    }
    for (; e < end; ++e) {
        int s = colidx[e];
        float wgt = dinv[s] * di;
        f16x4 v = hp[s * 128 + t];
        a0 += wgt * (float)v.x; a1 += wgt * (float)v.y;
        a2 += wgt * (float)v.z; a3 += wgt * (float)v.w;
    }
    f16x4 o;
    o.x = (_Float16)a0; o.y = (_Float16)a1; o.z = (_Float16)a2; o.w = (_Float16)a3;
    ((f16x4*)out)[node * 128 + t] = o;
}

// ---------------- 256^2 8-wave 4-phase GEMM, even staging + natural XCD map ---------
// C[M,N] = A[M,K] @ W[N,K]^T + bias, activation. N % 256 == 0, K % 64 == 0.
// Grid (N/256, M/256) with NO remap: linear dispatch round-robins XCDs, so with
// gx=8 each XCD owns ONE bn panel (1MB) -> B staging hits its own L2 (~200cyc).
// LDS per dbuf (64KB): A rows 0..255 x 64 halves at [0,16384), B at [16384,32768).
// T2 swizzle (R3-verified conflicts=0): read byte ^= ((row&7)<<4); staging source
// pre-swizzled with the same involution; linear gload_lds write + swz read = id.
// Phase schedule (tile t, buf c=t&1), exactly 1 half-tile (2 GLD) staged/phase:
//  P1: ds_read B(8)+A01(4); GLD Alo(t+1)->1-c.  [1-c fully drained at t start]
//  P2: ds_read A23;         GLD Ahi(t+1)->1-c.
//  P3: ds_read A45;         GLD Blo(t+2)->c.    [B region of c dead after P1 bar]
//  P4: ds_read A67;         GLD Bhi(t+2)->c; vmcnt(4) at end.
// Each phase: reads+GLD, BAR, setprio(1), 16 MFMA, setprio(0), BAR.
// vmcnt(4) drains B(t+1)+A(t+1), leaves B(t+2)'s 4 in flight. Never vmcnt(0).
#define FENCE() asm volatile("" ::: "memory")
#define BAR()   do { FENCE(); __builtin_amdgcn_s_barrier(); FENCE(); } while (0)
#define WAITV4() asm volatile("s_waitcnt vmcnt(4)" ::: "memory")
#define WAITV0() asm volatile("s_waitcnt vmcnt(0)" ::: "memory")
#define GLD(src, dst) __builtin_amdgcn_global_load_lds( \
    (const __attribute__((address_space(1))) void*)(src), \
    (__attribute__((address_space(3))) void*)(dst), 16, 0, 0)
#define LDF(base, row, kk) \
    (*(const f16x8*)((base) + ((((row) * 128 + (kk) * 64 + fqo)) ^ (((row) & 7) << 4))))
#define MM(mi, nj, A_, B_) \
    acc[mi][nj] = __builtin_amdgcn_mfma_f32_16x16x32_f16(A_, B_, acc[mi][nj], 0, 0, 0)

template <int ACT, typename OUT_T>
__global__ __launch_bounds__(512, 2) void k_gemm8(const half_t* __restrict__ A,
                                                  const half_t* __restrict__ W,
                                                  const float* __restrict__ bias,
                                                  OUT_T* __restrict__ C,
                                                  int M, int N, int K) {
    __shared__ half_t sm[2][32768];
    const int bn = blockIdx.x * 256;   // bn index == XCD under natural round-robin
    const int bm = blockIdx.y * 256;

    const int t = threadIdx.x;
    const int w = t >> 6, lane = t & 63;
    const int fr = lane & 15, fq = lane >> 4;
    const int fqo = fq * 16;
    const int wm = (w >> 2) * 128, wn = (w & 3) * 64;
    const int NT = K >> 6;

    // staging: load l covers half-range [l*4096 + w*512 + lane*8, +8) (linear LDS
    // write); source index pre-swizzled with the T2 involution.
    int q0 = w * 512 + lane * 8;
    int q1 = 4096 + q0;
    int s0 = q0 ^ (((q0 >> 6) & 7) << 3);
    int s1 = q1 ^ (((q1 >> 6) & 7) << 3);
    int r0 = s0 >> 6, c0 = s0 & 63;
    int r1 = s1 >> 6, c1 = s1 & 63;
    const half_t* gAlo0 = A + (size_t)min(bm + r0, M - 1) * K + c0;
    const half_t* gAlo1 = A + (size_t)min(bm + r1, M - 1) * K + c1;
    const half_t* gAhi0 = A + (size_t)min(bm + 128 + r0, M - 1) * K + c0;
    const half_t* gAhi1 = A + (size_t)min(bm + 128 + r1, M - 1) * K + c1;
    const half_t* gBlo0 = W + (size_t)(bn + r0) * K + c0;
    const half_t* gBlo1 = W + (size_t)(bn + r1) * K + c1;
    const half_t* gBhi0 = W + (size_t)(bn + 128 + r0) * K + c0;
    const half_t* gBhi1 = W + (size_t)(bn + 128 + r1) * K + c1;
    const int dst0 = w * 512;

#define STAGE_ALO(buf, kt) do {                                                \
    GLD(gAlo0 + (size_t)(kt) * 64, &sm[buf][dst0]);                            \
    GLD(gAlo1 + (size_t)(kt) * 64, &sm[buf][4096 + dst0]);                     \
} while (0)
#define STAGE_AHI(buf, kt) do {                                                \
    GLD(gAhi0 + (size_t)(kt) * 64, &sm[buf][8192 + dst0]);                     \
    GLD(gAhi1 + (size_t)(kt) * 64, &sm[buf][12288 + dst0]);                    \
} while (0)
#define STAGE_BLO(buf, kt) do {                                                \
    GLD(gBlo0 + (size_t)(kt) * 64, &sm[buf][16384 + dst0]);                    \
    GLD(gBlo1 + (size_t)(kt) * 64, &sm[buf][20480 + dst0]);                    \
} while (0)
#define STAGE_BHI(buf, kt) do {                                                \
    GLD(gBhi0 + (size_t)(kt) * 64, &sm[buf][24576 + dst0]);                    \
    GLD(gBhi1 + (size_t)(kt) * 64, &sm[buf][28672 + dst0]);                    \
} while (0)

    f32x4 acc[8][4] = {};

    // prologue: A0,B0 -> buf0 (8 GLD), B1 -> buf1 (4 GLD); vmcnt(4) lands A0,B0.
    STAGE_ALO(0, 0); STAGE_AHI(0, 0); STAGE_BLO(0, 0); STAGE_BHI(0, 0);
    {
        int k1 = (NT > 1) ? 1 : 0;
        STAGE_BLO(1, k1); STAGE_BHI(1, k1);
    }
    WAITV4();
    BAR();

#define TILE(cur, nxt, tt) do {                                                 \
    const char* smA = (const char*)&sm[cur][0];                                 \
    const char* smB = (const char*)&sm[cur][16384];                             \
    const int kA = ((tt) + 1 < NT) ? (tt) + 1 : NT - 1;                         \
    const int kB = ((tt) + 2 < NT) ? (tt) + 2 : NT - 1;                         \
    /* ---- P1: B all + A mi0,1; stage Alo(t+1)->nxt ---- */                    \
    f16x8 b00 = LDF(smB, wn + fr, 0),      b01 = LDF(smB, wn + fr, 1);          \
    f16x8 b10 = LDF(smB, wn + 16 + fr, 0), b11 = LDF(smB, wn + 16 + fr, 1);     \
    f16x8 b20 = LDF(smB, wn + 32 + fr, 0), b21 = LDF(smB, wn + 32 + fr, 1);     \
    f16x8 b30 = LDF(smB, wn + 48 + fr, 0), b31 = LDF(smB, wn + 48 + fr, 1);     \
    f16x8 a00 = LDF(smA, wm + fr, 0),      a01 = LDF(smA, wm + fr, 1);          \
    f16x8 a10 = LDF(smA, wm + 16 + fr, 0), a11 = LDF(smA, wm + 16 + fr, 1);     \
    STAGE_ALO(nxt, kA);                                                         \
    BAR();                                                                      \
    __builtin_amdgcn_s_setprio(1);                                              \
    MM(0, 0, a00, b00); MM(0, 1, a00, b10); MM(0, 2, a00, b20); MM(0, 3, a00, b30); \
    MM(0, 0, a01, b01); MM(0, 1, a01, b11); MM(0, 2, a01, b21); MM(0, 3, a01, b31); \
    MM(1, 0, a10, b00); MM(1, 1, a10, b10); MM(1, 2, a10, b20); MM(1, 3, a10, b30); \
    MM(1, 0, a11, b01); MM(1, 1, a11, b11); MM(1, 2, a11, b21); MM(1, 3, a11, b31); \
    __builtin_amdgcn_s_setprio(0);                                              \
    BAR();                                                                      \
    /* ---- P2: A mi2,3; stage Ahi(t+1)->nxt ---- */                            \
    f16x8 a20 = LDF(smA, wm + 32 + fr, 0), a21 = LDF(smA, wm + 32 + fr, 1);     \
    f16x8 a30 = LDF(smA, wm + 48 + fr, 0), a31 = LDF(smA, wm + 48 + fr, 1);     \
    STAGE_AHI(nxt, kA);                                                         \
    BAR();                                                                      \
    __builtin_amdgcn_s_setprio(1);                                              \
    MM(2, 0, a20, b00); MM(2, 1, a20, b10); MM(2, 2, a20, b20); MM(2, 3, a20, b30); \
    MM(2, 0, a21, b01); MM(2, 1, a21, b11); MM(2, 2, a21, b21); MM(2, 3, a21, b31); \
    MM(3, 0, a30, b00); MM(3, 1, a30, b10); MM(3, 2, a30, b20); MM(3, 3, a30, b30); \
    MM(3, 0, a31, b01); MM(3, 1, a31, b11); MM(3, 2, a31, b21); MM(3, 3, a31, b31); \
    __builtin_amdgcn_s_setprio(0);                                              \
    BAR();                                                                      \
    /* ---- P3: A mi4,5; stage Blo(t+2)->cur ---- */                            \
    f16x8 a40 = LDF(smA, wm + 64 + fr, 0), a41 = LDF(smA, wm + 64 + fr, 1);     \
    f16x8 a50 = LDF(smA, wm + 80 + fr, 0), a51 = LDF(smA, wm + 80 + fr, 1);     \
    STAGE_BLO(cur, kB);                                                         \
    BAR();                                                                      \
    __builtin_amdgcn_s_setprio(1);                                              \
    MM(4, 0, a40, b00); MM(4, 1, a40, b10); MM(4, 2, a40, b20); MM(4, 3, a40, b30); \
    MM(4, 0, a41, b01); MM(4, 1, a41, b11); MM(4, 2, a41, b21); MM(4, 3, a41, b31); \
    MM(5, 0, a50, b00); MM(5, 1, a50, b10); MM(5, 2, a50, b20); MM(5, 3, a50, b30); \
    MM(5, 0, a51, b01); MM(5, 1, a51, b11); MM(5, 2, a51, b21); MM(5, 3, a51, b31); \
    __builtin_amdgcn_s_setprio(0);                                              \
    BAR();                                                                      \
    /* ---- P4: A mi6,7; stage Bhi(t+2)->cur; counted wait ---- */              \
    f16x8 a60 = LDF(smA, wm + 96 + fr, 0),  a61 = LDF(smA, wm + 96 + fr, 1);    \
    f16x8 a70 = LDF(smA, wm + 112 + fr, 0), a71 = LDF(smA, wm + 112 + fr, 1);   \
    STAGE_BHI(cur, kB);                                                         \
    BAR();                                                                      \
    __builtin_amdgcn_s_setprio(1);                                              \
    MM(6, 0, a60, b00); MM(6, 1, a60, b10); MM(6, 2, a60, b20); MM(6, 3, a60, b30); \
    MM(6, 0, a61, b01); MM(6, 1, a61, b11); MM(6, 2, a61, b21); MM(6, 3, a61, b31); \
    MM(7, 0, a70, b00); MM(7, 1, a70, b10); MM(7, 2, a70, b20); MM(7, 3, a70, b30); \
    MM(7, 0, a71, b01); MM(7, 1, a71, b11); MM(7, 2, a71, b21); MM(7, 3, a71, b31); \
    __builtin_amdgcn_s_setprio(0);                                              \
    WAITV4();                                                                   \
    BAR();                                                                      \
} while (0)

    for (int tt = 0; tt < NT; tt += 2) {
        TILE(0, 1, tt);
        TILE(1, 0, tt + 1);
    }
    WAITV0();
#undef TILE
#undef STAGE_ALO
#undef STAGE_AHI
#undef STAGE_BLO
#undef STAGE_BHI

    // epilogue: D frag mapping col = lane&15, row = (lane>>4)*4 + r
    const int col0 = bn + wn + fr;
#pragma unroll
    for (int mi = 0; mi < 8; mi++) {
        int rb = bm + wm + mi * 16 + fq * 4;
#pragma unroll
        for (int nj = 0; nj < 4; nj++) {
            int col = col0 + nj * 16;
            float bv = bias[col];
#pragma unroll
            for (int r = 0; r < 4; r++) {
                int row = rb + r;
                if (row < M) {
                    float v = acc[mi][nj][r] + bv;
                    if (ACT == 1) v = fmaxf(v, 0.f);
                    if (ACT == 2) v = 0.5f * v * (1.f + erff(v * 0.70710678118f));
                    C[(size_t)row * N + col] = (OUT_T)v;
                }
            }
        }
    }
}

// ---------------- launch ----------------
extern "C" void kernel_launch(void* const* d_in, const int* in_sizes, int n_in,
                              void* d_out, int out_size, void* d_ws, size_t ws_size,
                              hipStream_t stream) {
    const float* x     = (const float*)d_in[0];
    const int*   eidx  = (const int*)d_in[1];
    const float* gn_w  = (const float*)d_in[2];
    const float* gn_b  = (const float*)d_in[3];
    const float* gn_ms = (const float*)d_in[4];
    const float* w1    = (const float*)d_in[5];
    const float* b1    = (const float*)d_in[6];
    const float* w2    = (const float*)d_in[7];
    const float* b2    = (const float*)d_in[8];
    const float* p1    = (const float*)d_in[9];
    const float* pb1   = (const float*)d_in[10];
    const float* p2    = (const float*)d_in[11];
    const float* pb2   = (const float*)d_in[12];

    const int Nn = in_sizes[0] / D_PROT;   // 50000
    const int E  = in_sizes[1] / 2;        // 400000
    const int M  = Nn;

    char* ws = (char*)d_ws;
    size_t off = 0;
    auto alloc = [&](size_t bytes) {
        void* p = ws + off;
        off += (bytes + 255) & ~(size_t)255;
        return p;
    };
    half_t* w1h    = (half_t*)alloc((size_t)D_PROT * D_PROT * 2);
    half_t* w2h    = (half_t*)alloc((size_t)D_PROT * D_PROT * 2);
    half_t* p1h    = (half_t*)alloc((size_t)D_TEXT * D_PROT * 2);
    half_t* p2h    = (half_t*)alloc((size_t)D_TEXT * D_TEXT * 2);
    int*    deg    = (int*)alloc((size_t)Nn * 4);
    float*  dinv   = (float*)alloc((size_t)Nn * 4);
    int*    rowptr = (int*)alloc((size_t)(Nn + 1) * 4);
    int*    fillc  = (int*)alloc((size_t)Nn * 4);
    int*    bsum   = (int*)alloc(1024);
    int*    boff   = (int*)alloc(1024);
    int*    colidx = (int*)alloc((size_t)E * 4);
    float*  sums   = (float*)alloc(D_PROT * 4);
    float*  sumsq  = (float*)alloc(D_PROT * 4);
    float*  gnab   = (float*)alloc(2 * D_PROT * 4);
    half_t* buf1   = (half_t*)alloc((size_t)Nn * D_PROT * 2);
    half_t* buf2   = (half_t*)alloc((size_t)Nn * D_PROT * 2);
    half_t* big    = (half_t*)alloc((size_t)Nn * D_TEXT * 2);

    const int* esrc = eidx;
    const int* edst = eidx + E;

    hipMemsetAsync(deg, 0, (size_t)Nn * 4, stream);
    hipMemsetAsync(fillc, 0, (size_t)Nn * 4, stream);
    hipMemsetAsync(rowptr, 0, (size_t)(Nn + 1) * 4, stream);
    hipMemsetAsync(sums, 0, D_PROT * 4, stream);
    hipMemsetAsync(sumsq, 0, D_PROT * 4, stream);

    k_cvt4<<<(D_PROT * D_PROT / 4 + 255) / 256, 256, 0, stream>>>(w1, w1h, D_PROT * D_PROT / 4);
    k_cvt4<<<(D_PROT * D_PROT / 4 + 255) / 256, 256, 0, stream>>>(w2, w2h, D_PROT * D_PROT / 4);
    k_cvt4<<<(D_TEXT * D_PROT / 4 + 255) / 256, 256, 0, stream>>>(p1, p1h, D_TEXT * D_PROT / 4);
    k_cvt4<<<(D_TEXT * D_TEXT / 4 + 255) / 256, 256, 0, stream>>>(p2, p2h, D_TEXT * D_TEXT / 4);

    int eb = (E + 255) / 256;
    int nb = (Nn + 255) / 256;
    k_deg<<<eb, 256, 0, stream>>>(edst, E, deg);
    k_dinv<<<nb, 256, 0, stream>>>(deg, dinv, Nn);
    k_blocksum<<<nb, 256, 0, stream>>>(deg, bsum, Nn);
    k_scan_bsum<<<1, 1, 0, stream>>>(bsum, boff, nb);
    k_scan_final<<<nb, 256, 0, stream>>>(deg, boff, rowptr, Nn);
    k_fill<<<eb, 256, 0, stream>>>(esrc, edst, E, rowptr, fillc, colidx);

    k_gnreduce<<<256, 256, 0, stream>>>(x, sums, sumsq, Nn);
    k_gnfinal<<<2, 256, 0, stream>>>(sums, sumsq, gn_w, gn_b, gn_ms, gnab, 1.0f / (float)Nn);
    int n4 = Nn * D_PROT / 4;
    k_gnnorm<<<(n4 + 255) / 256, 256, 0, stream>>>(x, gnab, buf1, n4);

    const int mt256 = (M + 255) / 256;

    // conv1: agg -> gemm+relu
    k_agg<<<Nn, 128, 0, stream>>>(buf1, buf2, rowptr, colidx, dinv);
    {
        dim3 g(D_PROT / 256, mt256);
        k_gemm8<1, half_t><<<g, 512, 0, stream>>>(buf2, w1h, b1, buf1, M, D_PROT, D_PROT);
    }
    // conv2
    k_agg<<<Nn, 128, 0, stream>>>(buf1, buf2, rowptr, colidx, dinv);
    {
        dim3 g(D_PROT / 256, mt256);
        k_gemm8<1, half_t><<<g, 512, 0, stream>>>(buf2, w2h, b2, buf1, M, D_PROT, D_PROT);
    }
    // proj1 + gelu
    {
        dim3 g(D_TEXT / 256, mt256);
        k_gemm8<2, half_t><<<g, 512, 0, stream>>>(buf1, p1h, pb1, big, M, D_TEXT, D_PROT);
    }
    // proj2 -> fp32 out
    {
        dim3 g(D_TEXT / 256, mt256);
        k_gemm8<0, float><<<g, 512, 0, stream>>>(big, p2h, pb2, (float*)d_out, M, D_TEXT, D_TEXT);
    }
}